// Round 1
// baseline (571.024 us; speedup 1.0000x reference)
//
#include <hip/hip_runtime.h>
#include <cstdint>
#include <cstddef>

// VmfVectorQuantizer fused kernel, round 1: fp32 VALU, wave-per-8-rows.
// rows N=65536, codes K=512, dim D=64.

namespace {
constexpr float kEpsG = 1e-10f;
constexpr float kEpsN = 1e-12f;
constexpr float kEpsP = 1e-7f;
}

__device__ __forceinline__ float wsum(float v) {
#pragma unroll
    for (int m = 1; m < 64; m <<= 1) v += __shfl_xor(v, m, 64);
    return v;
}
__device__ __forceinline__ float wmax(float v) {
#pragma unroll
    for (int m = 1; m < 64; m <<= 1) v = fmaxf(v, __shfl_xor(v, m, 64));
    return v;
}
// pack two positive floats to bf16 pair (RNE), a -> low 16, b -> high 16
__device__ __forceinline__ uint32_t pk_bf16(float a, float b) {
    uint32_t ua = __float_as_uint(a), ub = __float_as_uint(b);
    ua += 0x7fffu + ((ua >> 16) & 1u);
    ub += 0x7fffu + ((ub >> 16) & 1u);
    return (ua >> 16) | (ub & 0xffff0000u);
}
__device__ __forceinline__ float bflo(uint32_t u) { return __uint_as_float(u << 16); }
__device__ __forceinline__ float bfhi(uint32_t u) { return __uint_as_float(u & 0xffff0000u); }

// Kernel 1: normalize codebook rows; write cbN [512][64] and cbT [64][512].
__global__ __launch_bounds__(256) void k_norm(const float* __restrict__ cb,
                                              float* __restrict__ cbN,
                                              float* __restrict__ cbT) {
    const int row = blockIdx.x * 4 + (threadIdx.x >> 6);  // 0..511
    const int lane = threadIdx.x & 63;
    const float v = cb[row * 64 + lane];
    const float ss = wsum(v * v);
    const float nv = v / fmaxf(sqrtf(ss), kEpsN);
    cbN[row * 64 + lane] = nv;
    cbT[lane * 512 + row] = nv;
}

// Kernel 2: main fused kernel. 256 blocks x 256 threads (4 waves).
// Each wave independently processes 8 iterations of 8 rows.
__global__ __launch_bounds__(256, 3) void k_main(
    const float* __restrict__ z, const float* __restrict__ kq_ptr,
    const float* __restrict__ gum, const float* __restrict__ cbN,
    const float* __restrict__ cbT, float* __restrict__ out,
    float* __restrict__ g_avg, float* __restrict__ g_sc /*[0]=kldd,[1]=kldc*/) {
    __shared__ float znT[4][64][12];       // [wave][d][row(8)+pad]
    __shared__ uint32_t E2[4][8][260];     // [wave][row][k-pair bf16x2 (256)+pad]
    __shared__ float avg_lds[512];

    const int tid = threadIdx.x;
    const int w = tid >> 6;
    const int lane = tid & 63;
    const int dq = lane & 15;      // zq phase: d-quad index
    const int ko = lane >> 4;      // zq phase: k offset group 0..3
    const float kq = *kq_ptr;

    avg_lds[tid] = 0.f;
    avg_lds[tid + 256] = 0.f;

    float avgacc[8];               // per-lane p sums for k = 256c + 4*lane + i
#pragma unroll
    for (int i = 0; i < 8; ++i) avgacc[i] = 0.f;
    float kldd = 0.f, kldc = 0.f;

    for (int it = 0; it < 8; ++it) {
        const int r0 = blockIdx.x * 256 + (it * 4 + w) * 8;

        // ---- phase 1: load + L2-normalize 8 z-rows (lane = d) ----
#pragma unroll
        for (int r = 0; r < 8; ++r) {
            const float zv = z[(size_t)(r0 + r) * 64 + lane];
            const float ss = wsum(zv * zv);
            znT[w][lane][r] = zv / fmaxf(sqrtf(ss), kEpsN);
        }

        // ---- phase 2: logits acc[r][c*4+i] for k = 256c + 4*lane + i ----
        float acc[8][8];
#pragma unroll
        for (int r = 0; r < 8; ++r)
#pragma unroll
            for (int xi = 0; xi < 8; ++xi) acc[r][xi] = 0.f;

#pragma unroll 2
        for (int d = 0; d < 64; ++d) {
            const float4 cb0 = *(const float4*)(cbT + d * 512 + 4 * lane);
            const float4 cb1 = *(const float4*)(cbT + d * 512 + 256 + 4 * lane);
            const float4 za = *(const float4*)(&znT[w][d][0]);
            const float4 zb = *(const float4*)(&znT[w][d][4]);
            const float zr[8] = {za.x, za.y, za.z, za.w, zb.x, zb.y, zb.z, zb.w};
#pragma unroll
            for (int r = 0; r < 8; ++r) {
                acc[r][0] = fmaf(zr[r], cb0.x, acc[r][0]);
                acc[r][1] = fmaf(zr[r], cb0.y, acc[r][1]);
                acc[r][2] = fmaf(zr[r], cb0.z, acc[r][2]);
                acc[r][3] = fmaf(zr[r], cb0.w, acc[r][3]);
                acc[r][4] = fmaf(zr[r], cb1.x, acc[r][4]);
                acc[r][5] = fmaf(zr[r], cb1.y, acc[r][5]);
                acc[r][6] = fmaf(zr[r], cb1.z, acc[r][6]);
                acc[r][7] = fmaf(zr[r], cb1.w, acc[r][7]);
            }
        }

        // ---- phase 3: per-row softmax stats, gumbel-softmax, pack enc ----
#pragma unroll
        for (int r = 0; r < 8; ++r) {
            float x[8];
#pragma unroll
            for (int i = 0; i < 8; ++i) x[i] = kq * acc[r][i];
            float mx = x[0];
#pragma unroll
            for (int i = 1; i < 8; ++i) mx = fmaxf(mx, x[i]);
            mx = wmax(mx);
            float e[8], sl = 0.f;
#pragma unroll
            for (int i = 0; i < 8; ++i) { e[i] = __expf(x[i] - mx); sl += e[i]; }
            const float s1 = wsum(sl);
            const float inv1 = 1.0f / s1;
            const float ls1 = __logf(s1);
#pragma unroll
            for (int i = 0; i < 8; ++i) {
                const float p = e[i] * inv1;
                const float lp = (x[i] - mx) - ls1;
                kldd = fmaf(p, lp, kldd);
                avgacc[i] += p;
            }
            const size_t gb = (size_t)(r0 + r) * 512;
            const float4 u0 = *(const float4*)(gum + gb + 4 * lane);
            const float4 u1 = *(const float4*)(gum + gb + 256 + 4 * lane);
            const float uu[8] = {u0.x, u0.y, u0.z, u0.w, u1.x, u1.y, u1.z, u1.w};
            float y[8];
#pragma unroll
            for (int i = 0; i < 8; ++i) {
                const float g = -__logf(-__logf(uu[i] + kEpsG) + kEpsG);
                y[i] = 2.0f * (x[i] + g);  // (logit+g)/T, T=0.5
            }
            float m2 = y[0];
#pragma unroll
            for (int i = 1; i < 8; ++i) m2 = fmaxf(m2, y[i]);
            m2 = wmax(m2);
            float e2v[8], sl2 = 0.f;
#pragma unroll
            for (int i = 0; i < 8; ++i) { e2v[i] = __expf(y[i] - m2); sl2 += e2v[i]; }
            const float s2 = wsum(sl2);
            const float inv2 = 1.0f / s2;
#pragma unroll
            for (int i = 0; i < 8; ++i) e2v[i] *= inv2;
            uint2 pw0, pw1;
            pw0.x = pk_bf16(e2v[0], e2v[1]);
            pw0.y = pk_bf16(e2v[2], e2v[3]);
            pw1.x = pk_bf16(e2v[4], e2v[5]);
            pw1.y = pk_bf16(e2v[6], e2v[7]);
            *(uint2*)(&E2[w][r][2 * lane]) = pw0;          // k = 4*lane+0..3
            *(uint2*)(&E2[w][r][128 + 2 * lane]) = pw1;    // k = 256+4*lane+0..3
        }

        // ---- phase 4: z_q = Enc @ cbN.  lane = (dq, ko); 16 k per iter ----
        float a2[8][4];
#pragma unroll
        for (int r = 0; r < 8; ++r)
#pragma unroll
            for (int d = 0; d < 4; ++d) a2[r][d] = 0.f;

        for (int kb = 0; kb < 32; ++kb) {
            const int k0 = kb * 16 + ko * 4;  // this lane: codes k0..k0+3
            uint2 ed[8];
#pragma unroll
            for (int r = 0; r < 8; ++r) ed[r] = *(const uint2*)(&E2[w][r][k0 >> 1]);
            const float4 t0 = *(const float4*)(cbN + (size_t)(k0 + 0) * 64 + 4 * dq);
            const float4 t1 = *(const float4*)(cbN + (size_t)(k0 + 1) * 64 + 4 * dq);
            const float4 t2 = *(const float4*)(cbN + (size_t)(k0 + 2) * 64 + 4 * dq);
            const float4 t3 = *(const float4*)(cbN + (size_t)(k0 + 3) * 64 + 4 * dq);
#pragma unroll
            for (int r = 0; r < 8; ++r) {
                const float e0 = bflo(ed[r].x), e1 = bfhi(ed[r].x);
                const float e2q = bflo(ed[r].y), e3 = bfhi(ed[r].y);
                a2[r][0] = fmaf(e0, t0.x, a2[r][0]); a2[r][0] = fmaf(e1, t1.x, a2[r][0]);
                a2[r][0] = fmaf(e2q, t2.x, a2[r][0]); a2[r][0] = fmaf(e3, t3.x, a2[r][0]);
                a2[r][1] = fmaf(e0, t0.y, a2[r][1]); a2[r][1] = fmaf(e1, t1.y, a2[r][1]);
                a2[r][1] = fmaf(e2q, t2.y, a2[r][1]); a2[r][1] = fmaf(e3, t3.y, a2[r][1]);
                a2[r][2] = fmaf(e0, t0.z, a2[r][2]); a2[r][2] = fmaf(e1, t1.z, a2[r][2]);
                a2[r][2] = fmaf(e2q, t2.z, a2[r][2]); a2[r][2] = fmaf(e3, t3.z, a2[r][2]);
                a2[r][3] = fmaf(e0, t0.w, a2[r][3]); a2[r][3] = fmaf(e1, t1.w, a2[r][3]);
                a2[r][3] = fmaf(e2q, t2.w, a2[r][3]); a2[r][3] = fmaf(e3, t3.w, a2[r][3]);
            }
        }
        // reduce partial sums over the 4 ko groups
#pragma unroll
        for (int r = 0; r < 8; ++r)
#pragma unroll
            for (int d = 0; d < 4; ++d) {
                float v = a2[r][d];
                v += __shfl_xor(v, 16, 64);
                v += __shfl_xor(v, 32, 64);
                a2[r][d] = v;
            }
        // write z_q + accumulate kld_continuous (each element exactly once)
#pragma unroll
        for (int r = 0; r < 8; ++r) {
            if (ko == (r & 3)) {
                const size_t ob = (size_t)(r0 + r) * 64 + 4 * dq;
                float4 q4;
                q4.x = a2[r][0]; q4.y = a2[r][1]; q4.z = a2[r][2]; q4.w = a2[r][3];
                *(float4*)(out + ob) = q4;
                const float4 z4 = *(const float4*)(z + ob);
                kldc += z4.x * (z4.x - q4.x) + z4.y * (z4.y - q4.y)
                      + z4.z * (z4.z - q4.z) + z4.w * (z4.w - q4.w);
            }
        }
    }

    // ---- block + device reductions ----
    __syncthreads();
#pragma unroll
    for (int c = 0; c < 2; ++c)
#pragma unroll
        for (int i = 0; i < 4; ++i)
            atomicAdd(&avg_lds[c * 256 + 4 * lane + i], avgacc[c * 4 + i]);
    const float kd = wsum(kldd);
    const float kc = wsum(kldc) * kq;
    if (lane == 0) { atomicAdd(&g_sc[0], kd); atomicAdd(&g_sc[1], kc); }
    __syncthreads();
    atomicAdd(&g_avg[tid], avg_lds[tid]);
    atomicAdd(&g_avg[tid + 256], avg_lds[tid + 256]);
}

// Kernel 3: finalize loss + perplexity.
__global__ __launch_bounds__(512) void k_final(const float* __restrict__ g_avg,
                                               const float* __restrict__ g_sc,
                                               float* __restrict__ out) {
    __shared__ float red[8];
    const int tid = threadIdx.x;
    const float avg = g_avg[tid] * (1.0f / 65536.0f);
    const float t = avg * __logf(avg + kEpsP);
    const float s = wsum(t);
    if ((tid & 63) == 0) red[tid >> 6] = s;
    __syncthreads();
    if (tid == 0) {
        float tot = 0.f;
#pragma unroll
        for (int i = 0; i < 8; ++i) tot += red[i];
        out[4194304] = (g_sc[0] + g_sc[1]) * 0.125f;  // (kldd + kldc)/bs
        out[4194305] = __expf(-tot);
    }
}

extern "C" void kernel_launch(void* const* d_in, const int* in_sizes, int n_in,
                              void* d_out, int out_size, void* d_ws, size_t ws_size,
                              hipStream_t stream) {
    (void)in_sizes; (void)n_in; (void)out_size; (void)ws_size;
    const float* z   = (const float*)d_in[0];   // [8,1024,512]
    const float* kq  = (const float*)d_in[1];   // scalar
    const float* cb  = (const float*)d_in[2];   // [512,64]
    const float* gum = (const float*)d_in[3];   // [65536,512]
    float* out = (float*)d_out;
    float* ws  = (float*)d_ws;

    float* cbN   = ws;            // 32768 f32
    float* cbT   = ws + 32768;    // 32768 f32
    float* g_avg = ws + 65536;    // 512 f32
    float* g_sc  = ws + 66048;    // 2 f32

    hipMemsetAsync(g_avg, 0, 514 * sizeof(float), stream);
    k_norm<<<128, 256, 0, stream>>>(cb, cbN, cbT);
    k_main<<<256, 256, 0, stream>>>(z, kq, gum, cbN, cbT, out, g_avg, g_sc);
    k_final<<<1, 512, 0, stream>>>(g_avg, g_sc, out);
}

// Round 4
// 140.501 us; speedup vs baseline: 4.0642x; 4.0642x over previous
//
#include <hip/hip_runtime.h>
#include <cstdint>
#include <cstddef>

// VmfVectorQuantizer round 4: MFMA-based. N=65536 rows, K=512 codes, D=64.
// One wave per 16-row tile; GEMM1 (logits^T) and GEMM2 (zq) on
// mfma_f32_16x16x32_bf16; softmax fully in-register (lane owns one z-row).
// R4 fix: grid = 1024 blocks (64 rows/block), was 4096 -> OOB gum reads.

typedef __attribute__((ext_vector_type(8))) short short8;
typedef __attribute__((ext_vector_type(4))) float f32x4;

namespace {
constexpr float kEpsG = 1e-10f;
constexpr float kEpsN = 1e-12f;
constexpr float kEpsP = 1e-7f;
constexpr float kLog2e = 1.4426950408889634f;
constexpr float kLn2 = 0.6931471805599453f;
}

__device__ __forceinline__ float wsum64(float v) {
#pragma unroll
    for (int m = 1; m < 64; m <<= 1) v += __shfl_xor(v, m, 64);
    return v;
}
// RNE pack two f32 -> bf16 pair (a -> low16, b -> high16)
__device__ __forceinline__ uint32_t pk_bf16(float a, float b) {
    uint32_t ua = __float_as_uint(a), ub = __float_as_uint(b);
    ua += 0x7fffu + ((ua >> 16) & 1u);
    ub += 0x7fffu + ((ub >> 16) & 1u);
    return (ua >> 16) | (ub & 0xffff0000u);
}
__device__ __forceinline__ uint16_t bf16_rne(float a) {
    uint32_t ua = __float_as_uint(a);
    ua += 0x7fffu + ((ua >> 16) & 1u);
    return (uint16_t)(ua >> 16);
}
__device__ __forceinline__ float dot4(float4 v) {
    return v.x * v.x + v.y * v.y + v.z * v.z + v.w * v.w;
}

// ---- k_prep: L2-normalize codebook -> bf16 [512][64] and bf16-T [64][512]
__global__ __launch_bounds__(256) void k_prep(const float* __restrict__ cb,
                                              uint16_t* __restrict__ cbN,
                                              uint16_t* __restrict__ cbNT) {
    const int row = blockIdx.x * 4 + (threadIdx.x >> 6);  // 0..511
    const int lane = threadIdx.x & 63;
    const float v = cb[row * 64 + lane];
    const float ss = wsum64(v * v);
    const float nv = v / fmaxf(sqrtf(ss), kEpsN);
    const uint16_t h = bf16_rne(nv);
    cbN[row * 64 + lane] = h;
    cbNT[lane * 512 + row] = h;
}

// ---- k_main: one wave per 16-row tile. grid = 1024 x 256 (4 waves/block).
__global__ __launch_bounds__(256, 2) void k_main(
    const float* __restrict__ z, const float* __restrict__ kqp,
    const float* __restrict__ gum, const uint16_t* __restrict__ cbN,
    const uint16_t* __restrict__ cbNT, float* __restrict__ out,
    float* __restrict__ g_part) {
    __shared__ float avg_lds[4][512];

    const int tid = threadIdx.x;
    const int w = tid >> 6;
    const int l = tid & 63;
    const int g = l >> 4;    // 0..3
    const int rh = l & 15;   // 0..15
    const int gw = blockIdx.x * 4 + w;
    const int r0 = gw * 16;
    const int row = r0 + rh;           // this lane's z-row (fragment column)
    const float kq = *kqp;

    // ---- z load + L2 normalize; fold kq*log2e; build B-fragments (bf16x8 x2)
    const float* zr = z + (size_t)row * 64;
    const float4 a0 = *(const float4*)(zr + 8 * g);
    const float4 a1 = *(const float4*)(zr + 8 * g + 4);
    const float4 a2 = *(const float4*)(zr + 32 + 8 * g);
    const float4 a3 = *(const float4*)(zr + 36 + 8 * g);
    float ss = dot4(a0) + dot4(a1) + dot4(a2) + dot4(a3);
    ss += __shfl_xor(ss, 16, 64);
    ss += __shfl_xor(ss, 32, 64);
    const float sc = kq * kLog2e / fmaxf(sqrtf(ss), kEpsN);
    union U8 { short8 s; uint32_t u[4]; };
    U8 zb0, zb1;
    zb0.u[0] = pk_bf16(a0.x * sc, a0.y * sc);
    zb0.u[1] = pk_bf16(a0.z * sc, a0.w * sc);
    zb0.u[2] = pk_bf16(a1.x * sc, a1.y * sc);
    zb0.u[3] = pk_bf16(a1.z * sc, a1.w * sc);
    zb1.u[0] = pk_bf16(a2.x * sc, a2.y * sc);
    zb1.u[1] = pk_bf16(a2.z * sc, a2.w * sc);
    zb1.u[2] = pk_bf16(a3.x * sc, a3.y * sc);
    zb1.u[3] = pk_bf16(a3.z * sc, a3.w * sc);

    // ---- prefetch gumbel batch 0 (tiles 0..7)
    const float* ur = gum + (size_t)row * 512;
    float4 ubA[8], ubB[8];
#pragma unroll
    for (int tt = 0; tt < 8; ++tt)
        ubA[tt] = *(const float4*)(ur + 16 * tt + 4 * g);

    // ---- GEMM1: x2[c] = logit * kq * log2e, c = 16t + 4g + i (D-layout)
    float x2[128];
#pragma unroll
    for (int t = 0; t < 32; ++t) {
        const short8 ca0 = *(const short8*)(cbN + (rh + 16 * t) * 64 + 8 * g);
        const short8 ca1 = *(const short8*)(cbN + (rh + 16 * t) * 64 + 32 + 8 * g);
        f32x4 acc = {0.f, 0.f, 0.f, 0.f};
        acc = __builtin_amdgcn_mfma_f32_16x16x32_bf16(ca0, zb0.s, acc, 0, 0, 0);
        acc = __builtin_amdgcn_mfma_f32_16x16x32_bf16(ca1, zb1.s, acc, 0, 0, 0);
        x2[4 * t + 0] = acc[0];
        x2[4 * t + 1] = acc[1];
        x2[4 * t + 2] = acc[2];
        x2[4 * t + 3] = acc[3];
    }

    // ---- P1: row max (lane holds 128 codes of its row)
    float m2 = x2[0];
#pragma unroll
    for (int i = 1; i < 128; ++i) m2 = fmaxf(m2, x2[i]);
    m2 = fmaxf(m2, __shfl_xor(m2, 16, 64));
    m2 = fmaxf(m2, __shfl_xor(m2, 32, 64));

    // ---- P2: s = sum e, w = sum e*(x-m)  (log2 domain)
    float s = 0.f, wacc = 0.f;
#pragma unroll
    for (int i = 0; i < 128; ++i) {
        const float d = x2[i] - m2;
        const float e = exp2f(d);
        s += e;
        wacc = fmaf(e, d, wacc);
    }
    s += __shfl_xor(s, 16, 64);
    s += __shfl_xor(s, 32, 64);
    wacc += __shfl_xor(wacc, 16, 64);
    wacc += __shfl_xor(wacc, 32, 64);
    const float inv = 1.0f / s;
    float kldd = kLn2 * (wacc * inv - log2f(s));  // per-row (x4 lanes dup)

    // ---- P3: avg_probs partials: reduce p over the 16 rows, store to LDS
#pragma unroll
    for (int t = 0; t < 32; ++t) {
        float p0 = exp2f(x2[4 * t + 0] - m2) * inv;
        float p1 = exp2f(x2[4 * t + 1] - m2) * inv;
        float p2 = exp2f(x2[4 * t + 2] - m2) * inv;
        float p3 = exp2f(x2[4 * t + 3] - m2) * inv;
#pragma unroll
        for (int m = 1; m < 16; m <<= 1) {
            p0 += __shfl_xor(p0, m, 64);
            p1 += __shfl_xor(p1, m, 64);
            p2 += __shfl_xor(p2, m, 64);
            p3 += __shfl_xor(p3, m, 64);
        }
        if (rh == 0) {
            float4 pv = {p0, p1, p2, p3};
            *(float4*)&avg_lds[w][16 * t + 4 * g] = pv;
        }
    }

    // ---- P4: gumbel; v = x2 - log2(-ln(u+eps)+eps), double-buffered batches
#define GUMBEL_BATCH(B, UB)                                               \
    {                                                                     \
        _Pragma("unroll") for (int tt = 0; tt < 8; ++tt) {                \
            const int t = (B)*8 + tt;                                     \
            const float4 u4 = UB[tt];                                     \
            float lg, inr;                                                \
            lg = log2f(u4.x + kEpsG);                                     \
            inr = fmaf(lg, -kLn2, kEpsG);                                 \
            x2[4 * t + 0] -= log2f(inr);                                  \
            lg = log2f(u4.y + kEpsG);                                     \
            inr = fmaf(lg, -kLn2, kEpsG);                                 \
            x2[4 * t + 1] -= log2f(inr);                                  \
            lg = log2f(u4.z + kEpsG);                                     \
            inr = fmaf(lg, -kLn2, kEpsG);                                 \
            x2[4 * t + 2] -= log2f(inr);                                  \
            lg = log2f(u4.w + kEpsG);                                     \
            inr = fmaf(lg, -kLn2, kEpsG);                                 \
            x2[4 * t + 3] -= log2f(inr);                                  \
        }                                                                 \
    }

#pragma unroll
    for (int tt = 0; tt < 8; ++tt)
        ubB[tt] = *(const float4*)(ur + 16 * (8 + tt) + 4 * g);
    GUMBEL_BATCH(0, ubA)
#pragma unroll
    for (int tt = 0; tt < 8; ++tt)
        ubA[tt] = *(const float4*)(ur + 16 * (16 + tt) + 4 * g);
    GUMBEL_BATCH(1, ubB)
#pragma unroll
    for (int tt = 0; tt < 8; ++tt)
        ubB[tt] = *(const float4*)(ur + 16 * (24 + tt) + 4 * g);
    GUMBEL_BATCH(2, ubA)
    GUMBEL_BATCH(3, ubB)

    // ---- P5: max of v
    float m2p = x2[0];
#pragma unroll
    for (int i = 1; i < 128; ++i) m2p = fmaxf(m2p, x2[i]);
    m2p = fmaxf(m2p, __shfl_xor(m2p, 16, 64));
    m2p = fmaxf(m2p, __shfl_xor(m2p, 32, 64));
    const float n2m = -2.0f * m2p;

    // ---- P6: e2 = exp2(2v - 2m), s2; pack raw e2 as bf16 into x2[4t],[4t+1]
    float s2 = 0.f;
#pragma unroll
    for (int t = 0; t < 32; ++t) {
        const float e0 = exp2f(fmaf(2.0f, x2[4 * t + 0], n2m));
        const float e1 = exp2f(fmaf(2.0f, x2[4 * t + 1], n2m));
        const float e2 = exp2f(fmaf(2.0f, x2[4 * t + 2], n2m));
        const float e3 = exp2f(fmaf(2.0f, x2[4 * t + 3], n2m));
        s2 += e0 + e1 + e2 + e3;
        x2[4 * t + 0] = __uint_as_float(pk_bf16(e0, e1));
        x2[4 * t + 1] = __uint_as_float(pk_bf16(e2, e3));
    }
    s2 += __shfl_xor(s2, 16, 64);
    s2 += __shfl_xor(s2, 32, 64);
    const float inv2 = 1.0f / s2;

    // ---- GEMM2: zq = Enc @ cbN, A-frags gathered via shfl from D-layout
    f32x4 acc2[4];
#pragma unroll
    for (int dt = 0; dt < 4; ++dt) acc2[dt] = (f32x4){0.f, 0.f, 0.f, 0.f};
    const int srcA = rh + 16 * ((2 * g) & 3);
    const int srcB = rh + 16 * ((2 * g + 1) & 3);
    const bool hi = (g & 2) != 0;
#pragma unroll
    for (int ks = 0; ks < 16; ++ks) {
        const float a0lo = __shfl(x2[8 * ks + 0], srcA, 64);
        const float a0hi = __shfl(x2[8 * ks + 4], srcA, 64);
        const float a1lo = __shfl(x2[8 * ks + 1], srcA, 64);
        const float a1hi = __shfl(x2[8 * ks + 5], srcA, 64);
        const float b0lo = __shfl(x2[8 * ks + 0], srcB, 64);
        const float b0hi = __shfl(x2[8 * ks + 4], srcB, 64);
        const float b1lo = __shfl(x2[8 * ks + 1], srcB, 64);
        const float b1hi = __shfl(x2[8 * ks + 5], srcB, 64);
        U8 af;
        af.u[0] = __float_as_uint(hi ? a0hi : a0lo);
        af.u[1] = __float_as_uint(hi ? a1hi : a1lo);
        af.u[2] = __float_as_uint(hi ? b0hi : b0lo);
        af.u[3] = __float_as_uint(hi ? b1hi : b1lo);
#pragma unroll
        for (int dt = 0; dt < 4; ++dt) {
            const short8 bf =
                *(const short8*)(cbNT + (rh + 16 * dt) * 512 + 32 * ks + 8 * g);
            acc2[dt] = __builtin_amdgcn_mfma_f32_16x16x32_bf16(af.s, bf, acc2[dt], 0, 0, 0);
        }
    }

    // ---- epilogue: scale by inv2 (deferred softmax norm), write zq, kldc
    float iv[4];
#pragma unroll
    for (int i = 0; i < 4; ++i) iv[i] = __shfl(inv2, 4 * g + i, 64);
    float kldc = 0.f;
#pragma unroll
    for (int dt = 0; dt < 4; ++dt) {
#pragma unroll
        for (int i = 0; i < 4; ++i) {
            const float q = acc2[dt][i] * iv[i];
            const size_t oi = (size_t)(r0 + 4 * g + i) * 64 + rh + 16 * dt;
            out[oi] = q;
            const float zv = z[oi];
            kldc = fmaf(zv, zv - q, kldc);
        }
    }

    // ---- reductions
    const float kd = wsum64(kldd) * 0.25f;  // each row counted by 4 lanes
    const float kc = wsum64(kldc) * kq;
    const int slot = blockIdx.x & 63;
    if (l == 0) {
        atomicAdd(&g_part[slot * 514 + 512], kd);
        atomicAdd(&g_part[slot * 514 + 513], kc);
    }
    __syncthreads();
    const float v0 = avg_lds[0][tid] + avg_lds[1][tid] + avg_lds[2][tid] + avg_lds[3][tid];
    const float v1 = avg_lds[0][tid + 256] + avg_lds[1][tid + 256] +
                     avg_lds[2][tid + 256] + avg_lds[3][tid + 256];
    atomicAdd(&g_part[slot * 514 + tid], v0);
    atomicAdd(&g_part[slot * 514 + tid + 256], v1);
}

// ---- k_final: loss + perplexity
__global__ __launch_bounds__(512) void k_final(const float* __restrict__ g_part,
                                               float* __restrict__ out) {
    __shared__ float red[8];
    const int tid = threadIdx.x;
    float sacc = 0.f;
#pragma unroll 8
    for (int i = 0; i < 64; ++i) sacc += g_part[i * 514 + tid];
    const float avg = sacc * (1.0f / 65536.0f);
    const float t = avg * __logf(avg + kEpsP);
    const float sw = wsum64(t);
    if ((tid & 63) == 0) red[tid >> 6] = sw;
    __syncthreads();
    if (tid == 0) {
        float tot = 0.f;
#pragma unroll
        for (int i = 0; i < 8; ++i) tot += red[i];
        float sc0 = 0.f, sc1 = 0.f;
        for (int i = 0; i < 64; ++i) {
            sc0 += g_part[i * 514 + 512];
            sc1 += g_part[i * 514 + 513];
        }
        out[4194304] = (sc0 + sc1) * 0.125f;  // (kldd + kldc)/bs
        out[4194305] = __expf(-tot);
    }
}

extern "C" void kernel_launch(void* const* d_in, const int* in_sizes, int n_in,
                              void* d_out, int out_size, void* d_ws, size_t ws_size,
                              hipStream_t stream) {
    (void)in_sizes; (void)n_in; (void)out_size; (void)ws_size;
    const float* z   = (const float*)d_in[0];   // [8,1024,512]
    const float* kq  = (const float*)d_in[1];   // scalar
    const float* cb  = (const float*)d_in[2];   // [512,64]
    const float* gum = (const float*)d_in[3];   // [65536,512]
    float* out = (float*)d_out;

    uint16_t* cbN  = (uint16_t*)d_ws;                       // 64 KiB
    uint16_t* cbNT = cbN + 32768;                           // 64 KiB
    float* g_part  = (float*)(cbNT + 32768);                // 64*514 f32

    (void)hipMemsetAsync(g_part, 0, 64 * 514 * sizeof(float), stream);
    k_prep<<<128, 256, 0, stream>>>(cb, cbN, cbNT);
    k_main<<<1024, 256, 0, stream>>>(z, kq, gum, cbN, cbNT, out, g_part);
    k_final<<<1, 512, 0, stream>>>(g_part, out);
}

// Round 5
// 129.416 us; speedup vs baseline: 4.4123x; 1.0857x over previous
//
#include <hip/hip_runtime.h>
#include <cstdint>
#include <cstddef>

// VmfVectorQuantizer round 5: 2 waves cooperate per 16-row tile (codes split
// 256/256) to halve per-wave register state and double occupancy.
// N=65536 rows, K=512 codes, D=64. Blocks: 128 threads (2 waves), grid 4096.

typedef __attribute__((ext_vector_type(8))) short short8;
typedef __attribute__((ext_vector_type(4))) float f32x4;

namespace {
constexpr float kEpsG = 1e-10f;
constexpr float kEpsN = 1e-12f;
constexpr float kEpsP = 1e-7f;
constexpr float kLog2e = 1.4426950408889634f;
constexpr float kLn2 = 0.6931471805599453f;
constexpr int kSlots = 128;
constexpr int kStride = 520;  // 512 avg + scalars
}

__device__ __forceinline__ float wsum64(float v) {
#pragma unroll
    for (int m = 1; m < 64; m <<= 1) v += __shfl_xor(v, m, 64);
    return v;
}
__device__ __forceinline__ uint32_t pk_bf16(float a, float b) {
    uint32_t ua = __float_as_uint(a), ub = __float_as_uint(b);
    ua += 0x7fffu + ((ua >> 16) & 1u);
    ub += 0x7fffu + ((ub >> 16) & 1u);
    return (ua >> 16) | (ub & 0xffff0000u);
}
__device__ __forceinline__ uint16_t bf16_rne(float a) {
    uint32_t ua = __float_as_uint(a);
    ua += 0x7fffu + ((ua >> 16) & 1u);
    return (uint16_t)(ua >> 16);
}
__device__ __forceinline__ float dot4(float4 v) {
    return v.x * v.x + v.y * v.y + v.z * v.z + v.w * v.w;
}

// ---- k_prep: L2-normalize codebook -> bf16 [512][64] and bf16-T [64][512]
__global__ __launch_bounds__(256) void k_prep(const float* __restrict__ cb,
                                              uint16_t* __restrict__ cbN,
                                              uint16_t* __restrict__ cbNT) {
    const int row = blockIdx.x * 4 + (threadIdx.x >> 6);  // 0..511
    const int lane = threadIdx.x & 63;
    const float v = cb[row * 64 + lane];
    const float ss = wsum64(v * v);
    const float nv = v / fmaxf(sqrtf(ss), kEpsN);
    const uint16_t h = bf16_rne(nv);
    cbN[row * 64 + lane] = h;
    cbNT[lane * 512 + row] = h;
}

// ---- k_main: 2 waves per 16-row tile; wave W handles codes 256W..256W+255.
__global__ __launch_bounds__(128, 3) void k_main(
    const float* __restrict__ z, const float* __restrict__ kqp,
    const float* __restrict__ gum, const uint16_t* __restrict__ cbN,
    const uint16_t* __restrict__ cbNT, float* __restrict__ out,
    float* __restrict__ g_part) {
    __shared__ float avg_lds[512];
    __shared__ float cmbM[2][16], cmbS[2][16], cmbW[2][16], cmbP[2][16],
        cmbQ[2][16];
    __shared__ float4 accx[2][2][64];

    const int tid = threadIdx.x;
    const int W = tid >> 6;  // wave in block
    const int l = tid & 63;
    const int g = l >> 4;    // 0..3
    const int rh = l & 15;   // 0..15 (this lane's z-row within tile)
    const int r0 = blockIdx.x * 16;
    const int row = r0 + rh;
    const float kq = *kqp;

    // ---- z load + L2 normalize; fold kq*log2e; B-fragments (both waves same)
    const float* zr = z + (size_t)row * 64;
    const float4 a0 = *(const float4*)(zr + 8 * g);
    const float4 a1 = *(const float4*)(zr + 8 * g + 4);
    const float4 a2 = *(const float4*)(zr + 32 + 8 * g);
    const float4 a3 = *(const float4*)(zr + 36 + 8 * g);
    float ss = dot4(a0) + dot4(a1) + dot4(a2) + dot4(a3);
    ss += __shfl_xor(ss, 16, 64);
    ss += __shfl_xor(ss, 32, 64);
    const float sc = kq * kLog2e / fmaxf(sqrtf(ss), kEpsN);
    union U8 { short8 s; uint32_t u[4]; };
    U8 zb0, zb1;
    zb0.u[0] = pk_bf16(a0.x * sc, a0.y * sc);
    zb0.u[1] = pk_bf16(a0.z * sc, a0.w * sc);
    zb0.u[2] = pk_bf16(a1.x * sc, a1.y * sc);
    zb0.u[3] = pk_bf16(a1.z * sc, a1.w * sc);
    zb1.u[0] = pk_bf16(a2.x * sc, a2.y * sc);
    zb1.u[1] = pk_bf16(a2.z * sc, a2.w * sc);
    zb1.u[2] = pk_bf16(a3.x * sc, a3.y * sc);
    zb1.u[3] = pk_bf16(a3.z * sc, a3.w * sc);

    // ---- prefetch gumbel batch 0 (t=0..3); wave W covers codes 256W+16t+4g+i
    const float* ur = gum + (size_t)row * 512 + 256 * W;
    float4 ubA[4], ubB[4];
#pragma unroll
    for (int tt = 0; tt < 4; ++tt)
        ubA[tt] = *(const float4*)(ur + 16 * tt + 4 * g);

    // ---- GEMM1: x2[4t+i] = logit*kq*log2e for code 256W+16t+4g+i, row rh
    float x2[64];
#pragma unroll
    for (int t = 0; t < 16; ++t) {
        const uint16_t* cbr = cbN + (size_t)(256 * W + 16 * t + rh) * 64;
        const short8 ca0 = *(const short8*)(cbr + 8 * g);
        const short8 ca1 = *(const short8*)(cbr + 32 + 8 * g);
        f32x4 acc = {0.f, 0.f, 0.f, 0.f};
        acc = __builtin_amdgcn_mfma_f32_16x16x32_bf16(ca0, zb0.s, acc, 0, 0, 0);
        acc = __builtin_amdgcn_mfma_f32_16x16x32_bf16(ca1, zb1.s, acc, 0, 0, 0);
        x2[4 * t + 0] = acc[0];
        x2[4 * t + 1] = acc[1];
        x2[4 * t + 2] = acc[2];
        x2[4 * t + 3] = acc[3];
    }

    // ---- P1: row max across both waves
    float mh = x2[0];
#pragma unroll
    for (int i = 1; i < 64; ++i) mh = fmaxf(mh, x2[i]);
    mh = fmaxf(mh, __shfl_xor(mh, 16, 64));
    mh = fmaxf(mh, __shfl_xor(mh, 32, 64));
    if (g == 0) cmbM[W][rh] = mh;
    __syncthreads();
    const float m2 = fmaxf(cmbM[0][rh], cmbM[1][rh]);

    // ---- P2: softmax1 stats (log2 domain)
    float s = 0.f, wa = 0.f;
#pragma unroll
    for (int i = 0; i < 64; ++i) {
        const float d = x2[i] - m2;
        const float e = exp2f(d);
        s += e;
        wa = fmaf(e, d, wa);
    }
    s += __shfl_xor(s, 16, 64);
    s += __shfl_xor(s, 32, 64);
    wa += __shfl_xor(wa, 16, 64);
    wa += __shfl_xor(wa, 32, 64);
    if (g == 0) { cmbS[W][rh] = s; cmbW[W][rh] = wa; }
    __syncthreads();
    const float st = cmbS[0][rh] + cmbS[1][rh];
    const float wt = cmbW[0][rh] + cmbW[1][rh];
    const float inv = 1.0f / st;
    const float kldd = kLn2 * (wt * inv - log2f(st));  // per-row (4 lanes dup)

    // ---- P3: avg_probs partials (sum p over 16 rows), wave-disjoint codes
#pragma unroll
    for (int t = 0; t < 16; ++t) {
        float p0 = exp2f(x2[4 * t + 0] - m2) * inv;
        float p1 = exp2f(x2[4 * t + 1] - m2) * inv;
        float p2 = exp2f(x2[4 * t + 2] - m2) * inv;
        float p3 = exp2f(x2[4 * t + 3] - m2) * inv;
#pragma unroll
        for (int m = 1; m < 16; m <<= 1) {
            p0 += __shfl_xor(p0, m, 64);
            p1 += __shfl_xor(p1, m, 64);
            p2 += __shfl_xor(p2, m, 64);
            p3 += __shfl_xor(p3, m, 64);
        }
        if (rh == 0) {
            float4 pv = {p0, p1, p2, p3};
            *(float4*)&avg_lds[256 * W + 16 * t + 4 * g] = pv;
        }
    }

    // ---- P4: gumbel in place (y = x - log2(-ln(u+e)+e)) + running max
    float mp = -3.0e38f;
#define GB(UB, TB)                                                        \
    {                                                                     \
        _Pragma("unroll") for (int tt = 0; tt < 4; ++tt) {                \
            const int t = (TB) + tt;                                      \
            const float4 u4 = UB[tt];                                     \
            float y;                                                      \
            y = x2[4 * t + 0] -                                           \
                log2f(fmaf(log2f(u4.x + kEpsG), -kLn2, kEpsG));           \
            x2[4 * t + 0] = y; mp = fmaxf(mp, y);                         \
            y = x2[4 * t + 1] -                                           \
                log2f(fmaf(log2f(u4.y + kEpsG), -kLn2, kEpsG));           \
            x2[4 * t + 1] = y; mp = fmaxf(mp, y);                         \
            y = x2[4 * t + 2] -                                           \
                log2f(fmaf(log2f(u4.z + kEpsG), -kLn2, kEpsG));           \
            x2[4 * t + 2] = y; mp = fmaxf(mp, y);                         \
            y = x2[4 * t + 3] -                                           \
                log2f(fmaf(log2f(u4.w + kEpsG), -kLn2, kEpsG));           \
            x2[4 * t + 3] = y; mp = fmaxf(mp, y);                         \
        }                                                                 \
    }
#pragma unroll
    for (int tt = 0; tt < 4; ++tt)
        ubB[tt] = *(const float4*)(ur + 16 * (4 + tt) + 4 * g);
    GB(ubA, 0)
#pragma unroll
    for (int tt = 0; tt < 4; ++tt)
        ubA[tt] = *(const float4*)(ur + 16 * (8 + tt) + 4 * g);
    GB(ubB, 4)
#pragma unroll
    for (int tt = 0; tt < 4; ++tt)
        ubB[tt] = *(const float4*)(ur + 16 * (12 + tt) + 4 * g);
    GB(ubA, 8)
    GB(ubB, 12)

    mp = fmaxf(mp, __shfl_xor(mp, 16, 64));
    mp = fmaxf(mp, __shfl_xor(mp, 32, 64));
    if (g == 0) cmbP[W][rh] = mp;
    __syncthreads();
    const float m2p = fmaxf(cmbP[0][rh], cmbP[1][rh]);
    const float n2m = -2.0f * m2p;

    // ---- P6: e2 = exp2(2y - 2m), pack bf16 pairs; s2 across both waves
    float pf[32];
    float s2 = 0.f;
#pragma unroll
    for (int t = 0; t < 16; ++t) {
        const float e0 = exp2f(fmaf(2.0f, x2[4 * t + 0], n2m));
        const float e1 = exp2f(fmaf(2.0f, x2[4 * t + 1], n2m));
        const float e2 = exp2f(fmaf(2.0f, x2[4 * t + 2], n2m));
        const float e3 = exp2f(fmaf(2.0f, x2[4 * t + 3], n2m));
        s2 += e0 + e1 + e2 + e3;
        pf[2 * t + 0] = __uint_as_float(pk_bf16(e0, e1));
        pf[2 * t + 1] = __uint_as_float(pk_bf16(e2, e3));
    }
    s2 += __shfl_xor(s2, 16, 64);
    s2 += __shfl_xor(s2, 32, 64);
    if (g == 0) cmbQ[W][rh] = s2;
    __syncthreads();
    const float inv2 = 1.0f / (cmbQ[0][rh] + cmbQ[1][rh]);

    // ---- GEMM2 (partial over this wave's 256 codes): A gathered via shfl
    f32x4 acc2[4];
#pragma unroll
    for (int dt = 0; dt < 4; ++dt) acc2[dt] = (f32x4){0.f, 0.f, 0.f, 0.f};
    const int srcA = rh + 16 * ((2 * g) & 3);
    const int srcB = rh + 16 * ((2 * g + 1) & 3);
    const bool hi = (g & 2) != 0;
#pragma unroll
    for (int ks = 0; ks < 8; ++ks) {
        const float a0lo = __shfl(pf[4 * ks + 0], srcA, 64);
        const float a0hi = __shfl(pf[4 * ks + 2], srcA, 64);
        const float a1lo = __shfl(pf[4 * ks + 1], srcA, 64);
        const float a1hi = __shfl(pf[4 * ks + 3], srcA, 64);
        const float b0lo = __shfl(pf[4 * ks + 0], srcB, 64);
        const float b0hi = __shfl(pf[4 * ks + 2], srcB, 64);
        const float b1lo = __shfl(pf[4 * ks + 1], srcB, 64);
        const float b1hi = __shfl(pf[4 * ks + 3], srcB, 64);
        U8 af;
        af.u[0] = __float_as_uint(hi ? a0hi : a0lo);
        af.u[1] = __float_as_uint(hi ? a1hi : a1lo);
        af.u[2] = __float_as_uint(hi ? b0hi : b0lo);
        af.u[3] = __float_as_uint(hi ? b1hi : b1lo);
#pragma unroll
        for (int dt = 0; dt < 4; ++dt) {
            const short8 bf = *(const short8*)(cbNT + (size_t)(rh + 16 * dt) * 512 +
                                               256 * W + 32 * ks + 8 * g);
            acc2[dt] =
                __builtin_amdgcn_mfma_f32_16x16x32_bf16(af.s, bf, acc2[dt], 0, 0, 0);
        }
    }

    // ---- cross-wave partial sum: wave0 owns dt 0,1; wave1 owns dt 2,3
    if (W == 0) {
        accx[0][0][l] = make_float4(acc2[2][0], acc2[2][1], acc2[2][2], acc2[2][3]);
        accx[0][1][l] = make_float4(acc2[3][0], acc2[3][1], acc2[3][2], acc2[3][3]);
    } else {
        accx[1][0][l] = make_float4(acc2[0][0], acc2[0][1], acc2[0][2], acc2[0][3]);
        accx[1][1][l] = make_float4(acc2[1][0], acc2[1][1], acc2[1][2], acc2[1][3]);
    }
    __syncthreads();

    float iv[4];
#pragma unroll
    for (int i = 0; i < 4; ++i) iv[i] = __shfl(inv2, 4 * g + i, 64);
    float kldc = 0.f;

#define EPI(OV, XV, DT)                                                   \
    {                                                                     \
        const float oq[4] = {OV[0] + XV.x, OV[1] + XV.y, OV[2] + XV.z,    \
                             OV[3] + XV.w};                               \
        _Pragma("unroll") for (int i = 0; i < 4; ++i) {                   \
            const float q = oq[i] * iv[i];                                \
            const size_t oi = (size_t)(r0 + 4 * g + i) * 64 + rh + 16 * (DT); \
            out[oi] = q;                                                  \
            const float zv = z[oi];                                       \
            kldc = fmaf(zv, zv - q, kldc);                                \
        }                                                                 \
    }
    if (W == 0) {
        const float4 x0 = accx[1][0][l];
        const float4 x1 = accx[1][1][l];
        EPI(acc2[0], x0, 0)
        EPI(acc2[1], x1, 1)
    } else {
        const float4 x0 = accx[0][0][l];
        const float4 x1 = accx[0][1][l];
        EPI(acc2[2], x0, 2)
        EPI(acc2[3], x1, 3)
    }

    // ---- scalar + avg reductions
    const int slot = blockIdx.x & (kSlots - 1);
    float* gp = g_part + (size_t)slot * kStride;
    const float kc = wsum64(kldc) * kq;
    if (W == 0) {
        const float kd = wsum64(kldd) * 0.25f;  // 4 g-lanes duplicate each row
        if (l == 0) {
            atomicAdd(&gp[512], kd);
            atomicAdd(&gp[513], kc);
        }
    } else {
        if (l == 0) atomicAdd(&gp[513], kc);
    }
    // avg_lds fully written in P3 (barriers since then); flush 4 codes/thread
    const float4 av = *(const float4*)&avg_lds[tid * 4];
    atomicAdd(&gp[tid * 4 + 0], av.x);
    atomicAdd(&gp[tid * 4 + 1], av.y);
    atomicAdd(&gp[tid * 4 + 2], av.z);
    atomicAdd(&gp[tid * 4 + 3], av.w);
}

// ---- k_final: loss + perplexity
__global__ __launch_bounds__(512) void k_final(const float* __restrict__ g_part,
                                               float* __restrict__ out) {
    __shared__ float red[8];
    const int tid = threadIdx.x;
    float sacc = 0.f;
#pragma unroll 8
    for (int i = 0; i < kSlots; ++i) sacc += g_part[(size_t)i * kStride + tid];
    const float avg = sacc * (1.0f / 65536.0f);
    const float t = avg * __logf(avg + kEpsP);
    const float sw = wsum64(t);
    if ((tid & 63) == 0) red[tid >> 6] = sw;
    __syncthreads();
    if (tid == 0) {
        float tot = 0.f;
#pragma unroll
        for (int i = 0; i < 8; ++i) tot += red[i];
        float sc0 = 0.f, sc1 = 0.f;
        for (int i = 0; i < kSlots; ++i) {
            sc0 += g_part[(size_t)i * kStride + 512];
            sc1 += g_part[(size_t)i * kStride + 513];
        }
        out[4194304] = (sc0 + sc1) * 0.125f;  // (kldd + kldc)/bs
        out[4194305] = __expf(-tot);
    }
}

extern "C" void kernel_launch(void* const* d_in, const int* in_sizes, int n_in,
                              void* d_out, int out_size, void* d_ws, size_t ws_size,
                              hipStream_t stream) {
    (void)in_sizes; (void)n_in; (void)out_size; (void)ws_size;
    const float* z   = (const float*)d_in[0];   // [8,1024,512]
    const float* kq  = (const float*)d_in[1];   // scalar
    const float* cb  = (const float*)d_in[2];   // [512,64]
    const float* gum = (const float*)d_in[3];   // [65536,512]
    float* out = (float*)d_out;

    uint16_t* cbN  = (uint16_t*)d_ws;                       // 64 KiB
    uint16_t* cbNT = cbN + 32768;                           // 64 KiB
    float* g_part  = (float*)(cbNT + 32768);                // kSlots*kStride f32

    (void)hipMemsetAsync(g_part, 0, kSlots * kStride * sizeof(float), stream);
    k_prep<<<128, 256, 0, stream>>>(cb, cbN, cbNT);
    k_main<<<4096, 128, 0, stream>>>(z, kq, gum, cbN, cbNT, out, g_part);
    k_final<<<1, 512, 0, stream>>>(g_part, out);
}